// Round 1
// baseline (3436.934 us; speedup 1.0000x reference)
//
#include <hip/hip_runtime.h>
#include <cstdint>
#include <cstddef>

// RNG_MODE: 0 = jax partitionable threefry (bits = out0 ^ out1)  [modern jax default]
//           1 = partitionable, bits = out0
//           2 = partitionable, bits = out1
//           3 = legacy (non-partitionable) split-iota packing
#define RNG_MODE 0

namespace {
constexpr int kNB = 64;            // N*B
constexpr int kS = 32;
constexpr int kD = 256;
constexpr int kCH = 1024;
constexpr int kMmax = kNB * (kS - 1);   // 1984
}

__device__ float g_state[2][kNB * kS * kD];          // ping-pong state (64,32,256)
__device__ float g_inter[(size_t)kMmax * kCH];       // gelu(cat@w1+b1)
__device__ float g_cont[(size_t)kMmax * kCH];        // inter@w2+b2
__device__ float g_newh[(size_t)kMmax * kD];         // cell output
__device__ float g_s5[kMmax * 5];                    // per-position 5 window dots
__device__ float g_accu[kNB];
__device__ int g_selk[kNB];
__device__ float g_selv[kNB];

// ---------------- threefry2x32 (matches jax/_src/prng.py) ----------------
__device__ __forceinline__ void tf2x32(uint32_t k0, uint32_t k1, uint32_t x0,
                                       uint32_t x1, uint32_t& o0, uint32_t& o1) {
  uint32_t ks2 = k0 ^ k1 ^ 0x1BD11BDAu;
  x0 += k0; x1 += k1;
#define TF_ROT(v, r) (((v) << (r)) | ((v) >> (32 - (r))))
#define TF_RD(r) { x0 += x1; x1 = TF_ROT(x1, r); x1 ^= x0; }
  TF_RD(13) TF_RD(15) TF_RD(26) TF_RD(6)   x0 += k1;  x1 += ks2 + 1u;
  TF_RD(17) TF_RD(29) TF_RD(16) TF_RD(24)  x0 += ks2; x1 += k0 + 2u;
  TF_RD(13) TF_RD(15) TF_RD(26) TF_RD(6)   x0 += k0;  x1 += k1 + 3u;
  TF_RD(17) TF_RD(29) TF_RD(16) TF_RD(24)  x0 += k1;  x1 += ks2 + 4u;
  TF_RD(13) TF_RD(15) TF_RD(26) TF_RD(6)   x0 += ks2; x1 += k0 + 5u;
  o0 = x0; o1 = x1;
#undef TF_RD
#undef TF_ROT
}

// ---------------- reductions ----------------
__device__ __forceinline__ float blockSum256(float v, float* red4, int tid) {
#pragma unroll
  for (int o = 32; o > 0; o >>= 1) v += __shfl_down(v, o, 64);
  __syncthreads();
  if ((tid & 63) == 0) red4[tid >> 6] = v;
  __syncthreads();
  return red4[0] + red4[1] + red4[2] + red4[3];
}
__device__ __forceinline__ float waveMax64(float v) {
#pragma unroll
  for (int o = 32; o > 0; o >>= 1) v = fmaxf(v, __shfl_xor(v, o, 64));
  return v;
}
__device__ __forceinline__ float waveSum64(float v) {
#pragma unroll
  for (int o = 32; o > 0; o >>= 1) v += __shfl_xor(v, o, 64);
  return v;
}

// ---------------- word embedding + LN, replicate to B copies ----------------
__global__ __launch_bounds__(256) void k_embed(const float* __restrict__ x,
                                               const float* __restrict__ wW,
                                               const float* __restrict__ wb,
                                               const float* __restrict__ lng,
                                               const float* __restrict__ lnb,
                                               int cur) {
  int row = blockIdx.x;  // n*32 + s, 512 rows
  int d = threadIdx.x;
  __shared__ float xs[kD];
  __shared__ float red4[4];
  xs[d] = x[row * kD + d];
  __syncthreads();
  float acc = wb[d];
  for (int k = 0; k < kD; ++k) acc = fmaf(xs[k], wW[k * kD + d], acc);
  float mean = blockSum256(acc, red4, d) * (1.0f / 256.0f);
  float cen = acc - mean;
  float var = blockSum256(cen * cen, red4, d) * (1.0f / 256.0f);
  float o = cen / sqrtf(var + 1e-5f) * lng[d] + lnb[d];
  int n = row >> 5, s = row & 31;
  float* st = g_state[cur];
#pragma unroll
  for (int bb = 0; bb < 4; ++bb) st[((n * 4 + bb) * kS + s) * kD + d] = o;
  if (row == 0 && d < kNB) g_accu[d] = 0.0f;
}

// ---------------- GEMM1: inter = gelu(cat @ w1 + b1) ----------------
// cat row m=(b,j) is the contiguous 512 floats state[b*8192 + j*256 ...]
__global__ __launch_bounds__(256) void k_gemm1(const float* __restrict__ w1,
                                               const float* __restrict__ b1,
                                               int Sc, int cur) {
  const float* __restrict__ A = g_state[cur];
  __shared__ float As[16][68];   // [k][m], padded
  __shared__ float Bs[16][64];   // [k][n]
  int tid = threadIdx.x;
  int nBase = blockIdx.x * 64;
  int mBase = blockIdx.y * 64;
  int ac = tid & 15, ar = tid >> 4;   // A load: col-within-ktile, row
  int bc = tid & 63, br = tid >> 6;   // B load
  int tx = tid & 15, ty = tid >> 4;   // compute microtile
  int aoff[4];
#pragma unroll
  for (int s = 0; s < 4; ++s) {
    int row = mBase + ar + s * 16;
    int b = row / Sc, j = row - b * Sc;
    aoff[s] = b * 8192 + j * 256;
  }
  float acc[4][4] = {};
  for (int k0 = 0; k0 < 512; k0 += 16) {
#pragma unroll
    for (int s = 0; s < 4; ++s) As[ac][ar + s * 16] = A[aoff[s] + k0 + ac];
#pragma unroll
    for (int s = 0; s < 4; ++s)
      Bs[br + s * 4][bc] = w1[(size_t)(k0 + br + s * 4) * 1024 + nBase + bc];
    __syncthreads();
#pragma unroll
    for (int kk = 0; kk < 16; ++kk) {
      float4 a4 = *(const float4*)&As[kk][ty * 4];
      float4 b4 = *(const float4*)&Bs[kk][tx * 4];
      float av[4] = {a4.x, a4.y, a4.z, a4.w};
      float bv[4] = {b4.x, b4.y, b4.z, b4.w};
#pragma unroll
      for (int ii = 0; ii < 4; ++ii)
#pragma unroll
        for (int jj = 0; jj < 4; ++jj)
          acc[ii][jj] = fmaf(av[ii], bv[jj], acc[ii][jj]);
    }
    __syncthreads();
  }
#pragma unroll
  for (int ii = 0; ii < 4; ++ii) {
    int m = mBase + ty * 4 + ii;
#pragma unroll
    for (int jj = 0; jj < 4; ++jj) {
      int n = nBase + tx * 4 + jj;
      float v = acc[ii][jj] + b1[n];
      float ge = 0.5f * v * (1.0f + erff(v * 0.70710678118654752440f));
      g_inter[(size_t)m * 1024 + n] = ge;
    }
  }
}

// ---------------- GEMM2: cont = inter @ w2 + b2 ----------------
__global__ __launch_bounds__(256) void k_gemm2(const float* __restrict__ w2,
                                               const float* __restrict__ b2,
                                               int Sc) {
  __shared__ float As[16][68];
  __shared__ float Bs[16][64];
  int tid = threadIdx.x;
  int nBase = blockIdx.x * 64;
  int mBase = blockIdx.y * 64;
  int ac = tid & 15, ar = tid >> 4;
  int bc = tid & 63, br = tid >> 6;
  int tx = tid & 15, ty = tid >> 4;
  float acc[4][4] = {};
  for (int k0 = 0; k0 < 1024; k0 += 16) {
#pragma unroll
    for (int s = 0; s < 4; ++s)
      As[ac][ar + s * 16] = g_inter[(size_t)(mBase + ar + s * 16) * 1024 + k0 + ac];
#pragma unroll
    for (int s = 0; s < 4; ++s)
      Bs[br + s * 4][bc] = w2[(size_t)(k0 + br + s * 4) * 1024 + nBase + bc];
    __syncthreads();
#pragma unroll
    for (int kk = 0; kk < 16; ++kk) {
      float4 a4 = *(const float4*)&As[kk][ty * 4];
      float4 b4 = *(const float4*)&Bs[kk][tx * 4];
      float av[4] = {a4.x, a4.y, a4.z, a4.w};
      float bv[4] = {b4.x, b4.y, b4.z, b4.w};
#pragma unroll
      for (int ii = 0; ii < 4; ++ii)
#pragma unroll
        for (int jj = 0; jj < 4; ++jj)
          acc[ii][jj] = fmaf(av[ii], bv[jj], acc[ii][jj]);
    }
    __syncthreads();
  }
#pragma unroll
  for (int ii = 0; ii < 4; ++ii) {
    int m = mBase + ty * 4 + ii;
#pragma unroll
    for (int jj = 0; jj < 4; ++jj) {
      int n = nBase + tx * 4 + jj;
      g_cont[(size_t)m * 1024 + n] = acc[ii][jj] + b2[n];
    }
  }
}

// ---------------- gates + LN + decision window dots ----------------
__global__ __launch_bounds__(256) void k_cell(const float* __restrict__ imask,
                                              const float* __restrict__ ln2g,
                                              const float* __restrict__ ln2b,
                                              const float* __restrict__ decW,
                                              int Sc, int step, int cur) {
  int m = blockIdx.x;
  int d = threadIdx.x;
  int b = m / Sc, j = m - b * Sc;
  const float* st = g_state[cur];
  const float* crow = g_cont + (size_t)m * kCH;
  float c0 = crow[d], c1 = crow[kD + d], c2 = crow[2 * kD + d], c3 = crow[3 * kD + d];
  float l = st[b * 8192 + j * kD + d];
  float r = st[b * 8192 + (j + 1) * kD + d];
  float f1 = 1.0f / (1.0f + expf(-c0));
  float f2 = 1.0f / (1.0f + expf(-c1));
  float ig = 1.0f / (1.0f + expf(-c2));
  float pre = f1 * l + f2 * r + ig * c3;
  __shared__ float red4[4];
  __shared__ float w5[4][5];
  float mean = blockSum256(pre, red4, d) * (1.0f / 256.0f);
  float cen = pre - mean;
  float var = blockSum256(cen * cen, red4, d) * (1.0f / 256.0f);
  float nh = cen / sqrtf(var + 1e-5f) * ln2g[d] + ln2b[d];
  g_newh[(size_t)m * kD + d] = nh;
  // decision scores on masked nh
  float mv = imask[(b >> 2) * kS + step + 1 + j];
  float nhm = nh * mv;
  float pv[5];
#pragma unroll
  for (int t = 0; t < 5; ++t) pv[t] = nhm * decW[t * kD + d];
#pragma unroll
  for (int t = 0; t < 5; ++t)
#pragma unroll
    for (int o = 32; o > 0; o >>= 1) pv[t] += __shfl_down(pv[t], o, 64);
  __syncthreads();
  if ((d & 63) == 0) {
#pragma unroll
    for (int t = 0; t < 5; ++t) w5[d >> 6][t] = pv[t];
  }
  __syncthreads();
  if (d < 5) g_s5[m * 5 + d] = w5[0][d] + w5[1][d] + w5[2][d] + w5[3][d];
}

// ---------------- per-sequence Gumbel decision (one wave per b) ----------------
__global__ void k_decide(const float* __restrict__ imask,
                         const float* __restrict__ decb, int Sc, int step) {
  int b = blockIdx.x;
  int j = threadIdx.x;  // 64 lanes
  bool act = j < Sc;
  float mv = 0.0f, lg = 0.0f;
  if (act) {
    mv = imask[(b >> 2) * kS + step + 1 + j];
    const float* S5 = g_s5 + (size_t)b * Sc * 5;
    float t = decb[0];
    if (j >= 2) t += S5[(j - 2) * 5 + 0];
    if (j >= 1) t += S5[(j - 1) * 5 + 1];
    t += S5[j * 5 + 2];
    if (j + 1 < Sc) t += S5[(j + 1) * 5 + 3];
    if (j + 2 < Sc) t += S5[(j + 2) * 5 + 4];
    lg = t / 35.77708763999664f;  // / sqrt(5*D)
  }
  // gumbel noise, bit-exact jax threefry
  uint32_t fk0, fk1, o0, o1;
  tf2x32(0u, 1234u, 0u, (uint32_t)step, fk0, fk1);  // fold_in(key(1234), step)
  uint32_t idx = (uint32_t)(b * Sc + j);
  uint32_t bits;
#if RNG_MODE == 0
  tf2x32(fk0, fk1, 0u, idx, o0, o1);
  bits = o0 ^ o1;
#elif RNG_MODE == 1
  tf2x32(fk0, fk1, 0u, idx, o0, o1);
  bits = o0;
#elif RNG_MODE == 2
  tf2x32(fk0, fk1, 0u, idx, o0, o1);
  bits = o1;
#else
  {
    uint32_t h = (uint32_t)(32 * Sc);
    if (idx < h) { tf2x32(fk0, fk1, idx, idx + h, o0, o1); bits = o0; }
    else         { tf2x32(fk0, fk1, idx - h, idx, o0, o1); bits = o1; }
  }
#endif
  float u = __uint_as_float((bits >> 9) | 0x3f800000u) - 1.0f;
  float gum = -logf(-logf(u + 1e-20f) + 1e-20f);
  float z = lg + gum;

  // y_soft = masked softmax of logits+g
  float zm = waveMax64(act ? z : -3.0e38f);
  float e = act ? expf(z - zm) : 0.0f;
  float p = e / waveSum64(e);
  float y = act ? (p * mv + 1e-20f) : 0.0f;
  float ys = y / waveSum64(y);

  // argmax (first occurrence)
  float av = act ? ys : -1.0f;
  int ai = j;
#pragma unroll
  for (int o = 32; o > 0; o >>= 1) {
    float ov = __shfl_xor(av, o, 64);
    int oi = __shfl_xor(ai, o, 64);
    if (ov > av || (ov == av && oi < ai)) { av = ov; ai = oi; }
  }

  // no-gumbel masked softmax
  float lm = waveMax64(act ? lg : -3.0e38f);
  float e2 = act ? expf(lg - lm) : 0.0f;
  float p2 = e2 / waveSum64(e2);
  float y2 = act ? (p2 * mv + 1e-20f) : 0.0f;
  float ps = y2 / waveSum64(y2);

  float ysk = __shfl(ys, ai, 64);
  float psk = __shfl(ps, ai, 64);
  float selv = (1.0f - ysk) + ysk;  // straight-through exact value at k
  if (j == 0) {
    float done = imask[(b >> 2) * kS + step + 1];
    float score = selv * psk;
    g_accu[b] += done * logf(score + 1e-20f);
    g_selk[b] = ai;
    g_selv[b] = selv;
  }
}

// ---------------- merge/compact state ----------------
__global__ __launch_bounds__(256) void k_merge(const float* __restrict__ imask,
                                               int Sc, int step, int isLast,
                                               int cur) {
  int e = blockIdx.x * 256 + threadIdx.x;
  int d = e & (kD - 1);
  int m = e >> 8;
  int b = m / Sc, j = m - b * Sc;
  const float* so = g_state[cur];
  float* sn = g_state[cur ^ 1];
  float done = imask[(b >> 2) * kS + step + 1];
  float nh = g_newh[(size_t)m * kD + d];
  float oldl = so[b * 8192 + j * kD + d];
  float merged;
  if (isLast) {
    merged = nh;
  } else {
    int k = g_selk[b];
    float sv = g_selv[b];
    float selj = (j == k) ? sv : 0.0f;
    float cs = (j >= k) ? sv : 0.0f;
    float oldr = so[b * 8192 + (j + 1) * kD + d];
    merged = selj * nh + (1.0f - cs) * oldl + (cs - selj) * oldr;
  }
  sn[b * 8192 + j * kD + d] = done * merged + (1.0f - done) * oldl;
}

// ---------------- final weighted sum over B ----------------
__global__ __launch_bounds__(256) void k_final(float* __restrict__ out, int cur) {
  int n = blockIdx.x, d = threadIdx.x;
  float a0 = g_accu[n * 4 + 0], a1 = g_accu[n * 4 + 1];
  float a2 = g_accu[n * 4 + 2], a3 = g_accu[n * 4 + 3];
  float mx = fmaxf(fmaxf(a0, a1), fmaxf(a2, a3));
  float e0 = expf(a0 - mx), e1 = expf(a1 - mx), e2 = expf(a2 - mx), e3 = expf(a3 - mx);
  float s = e0 + e1 + e2 + e3;
  const float* st = g_state[cur];
  float h0 = st[(n * 4 + 0) * 8192 + d];
  float h1 = st[(n * 4 + 1) * 8192 + d];
  float h2 = st[(n * 4 + 2) * 8192 + d];
  float h3 = st[(n * 4 + 3) * 8192 + d];
  out[n * kD + d] = (e0 / s) * h0 + (e1 / s) * h1 + (e2 / s) * h2 + (e3 / s) * h3;
}

extern "C" void kernel_launch(void* const* d_in, const int* in_sizes, int n_in,
                              void* d_out, int out_size, void* d_ws, size_t ws_size,
                              hipStream_t stream) {
  (void)in_sizes; (void)n_in; (void)d_ws; (void)ws_size; (void)out_size;
  const float* x = (const float*)d_in[0];
  const float* imask = (const float*)d_in[1];
  const float* wW = (const float*)d_in[2];
  const float* wb = (const float*)d_in[3];
  const float* lng = (const float*)d_in[4];
  const float* lnb = (const float*)d_in[5];
  const float* w1 = (const float*)d_in[6];
  const float* b1 = (const float*)d_in[7];
  const float* w2 = (const float*)d_in[8];
  const float* b2 = (const float*)d_in[9];
  const float* ln2g = (const float*)d_in[10];
  const float* ln2b = (const float*)d_in[11];
  const float* decW = (const float*)d_in[12];
  const float* decb = (const float*)d_in[13];
  float* out = (float*)d_out;

  int cur = 0;
  k_embed<<<dim3(512), dim3(256), 0, stream>>>(x, wW, wb, lng, lnb, cur);
  for (int i = 0; i < kS - 1; ++i) {
    int Sc = kS - 1 - i;
    k_gemm1<<<dim3(16, Sc), dim3(256), 0, stream>>>(w1, b1, Sc, cur);
    k_gemm2<<<dim3(16, Sc), dim3(256), 0, stream>>>(w2, b2, Sc);
    k_cell<<<dim3(kNB * Sc), dim3(256), 0, stream>>>(imask, ln2g, ln2b, decW, Sc, i, cur);
    if (i < kS - 2)
      k_decide<<<dim3(kNB), dim3(64), 0, stream>>>(imask, decb, Sc, i);
    k_merge<<<dim3(kNB * Sc), dim3(256), 0, stream>>>(imask, Sc, i, (i == kS - 2) ? 1 : 0, cur);
    cur ^= 1;
  }
  k_final<<<dim3(16), dim3(256), 0, stream>>>(out, cur);
}

// Round 2
// 1407.932 us; speedup vs baseline: 2.4411x; 2.4411x over previous
//
#include <hip/hip_runtime.h>
#include <cstdint>
#include <cstddef>

namespace {
constexpr int kNB = 64;            // N*B sequences
constexpr int kS = 32;
constexpr int kD = 256;
constexpr int kCH = 1024;
constexpr int kNseq = 16;          // N
constexpr int kP0 = 31;            // pairs at step 0
constexpr int kM0 = kNseq * kP0;   // 496 unique rows at step 0
}

// ping-pong state (64,32,256); buffer parity: step i reads [i&1], merge(i) writes [(i+1)&1]
__device__ float g_state[2][kNB * kS * kD];
__device__ float g_nh[2][kNB * kP0 * kD];      // per-b pair rows
__device__ float g_s5[2][kNB * kP0 * 5];
__device__ float g_nh0[kM0 * kD];              // step-0 n-indexed pair rows
__device__ float g_s50[kM0 * 5];
__device__ float g_inter0[(size_t)kM0 * kCH];
__device__ float g_cont0[(size_t)kM0 * kCH];
__device__ float g_interI[128 * kCH];          // incremental slots
__device__ float g_contP[4][128 * kCH];        // split-K partials
__device__ float g_accu[kNB];
__device__ int g_slots[2 * kNB];               // new-index recompute rows, -1 = none

// ---------------- threefry2x32 (matches jax, RNG verified passing) ----------------
__device__ __forceinline__ void tf2x32(uint32_t k0, uint32_t k1, uint32_t x0,
                                       uint32_t x1, uint32_t& o0, uint32_t& o1) {
  uint32_t ks2 = k0 ^ k1 ^ 0x1BD11BDAu;
  x0 += k0; x1 += k1;
#define TF_ROT(v, r) (((v) << (r)) | ((v) >> (32 - (r))))
#define TF_RD(r) { x0 += x1; x1 = TF_ROT(x1, r); x1 ^= x0; }
  TF_RD(13) TF_RD(15) TF_RD(26) TF_RD(6)   x0 += k1;  x1 += ks2 + 1u;
  TF_RD(17) TF_RD(29) TF_RD(16) TF_RD(24)  x0 += ks2; x1 += k0 + 2u;
  TF_RD(13) TF_RD(15) TF_RD(26) TF_RD(6)   x0 += k0;  x1 += k1 + 3u;
  TF_RD(17) TF_RD(29) TF_RD(16) TF_RD(24)  x0 += k1;  x1 += ks2 + 4u;
  TF_RD(13) TF_RD(15) TF_RD(26) TF_RD(6)   x0 += ks2; x1 += k0 + 5u;
  o0 = x0; o1 = x1;
#undef TF_RD
#undef TF_ROT
}

__device__ __forceinline__ float blockSum256(float v, float* red4, int tid) {
#pragma unroll
  for (int o = 32; o > 0; o >>= 1) v += __shfl_down(v, o, 64);
  __syncthreads();
  if ((tid & 63) == 0) red4[tid >> 6] = v;
  __syncthreads();
  return red4[0] + red4[1] + red4[2] + red4[3];
}
__device__ __forceinline__ float waveMax64(float v) {
#pragma unroll
  for (int o = 32; o > 0; o >>= 1) v = fmaxf(v, __shfl_xor(v, o, 64));
  return v;
}
__device__ __forceinline__ float waveSum64(float v) {
#pragma unroll
  for (int o = 32; o > 0; o >>= 1) v += __shfl_xor(v, o, 64);
  return v;
}
__device__ __forceinline__ float geluf(float v) {
  return 0.5f * v * (1.0f + erff(v * 0.70710678118654752440f));
}

// ---------------- embed + LN, replicate to B copies ----------------
__global__ __launch_bounds__(256) void k_embed(const float* __restrict__ x,
                                               const float* __restrict__ wW,
                                               const float* __restrict__ wb,
                                               const float* __restrict__ lng,
                                               const float* __restrict__ lnb) {
  int row = blockIdx.x;  // n*32 + s
  int d = threadIdx.x;
  __shared__ float xs[kD];
  __shared__ float red4[4];
  xs[d] = x[row * kD + d];
  __syncthreads();
  float acc = wb[d];
  for (int k = 0; k < kD; ++k) acc = fmaf(xs[k], wW[k * kD + d], acc);
  float mean = blockSum256(acc, red4, d) * (1.0f / 256.0f);
  float cen = acc - mean;
  float var = blockSum256(cen * cen, red4, d) * (1.0f / 256.0f);
  float o = cen / sqrtf(var + 1e-5f) * lng[d] + lnb[d];
  int n = row >> 5, s = row & 31;
  float* st = g_state[0];
#pragma unroll
  for (int bb = 0; bb < 4; ++bb) st[((n * 4 + bb) * kS + s) * kD + d] = o;
  if (row == 0 && d < kNB) g_accu[d] = 0.0f;
}

// ---------------- step-0 full GEMMs on 496 unique rows ----------------
__global__ __launch_bounds__(256) void k_g1full(const float* __restrict__ w1,
                                                const float* __restrict__ b1) {
  __shared__ float As[16][68];
  __shared__ float Bs[16][64];
  int tid = threadIdx.x;
  int nBase = blockIdx.x * 64, mBase = blockIdx.y * 64;
  int ac = tid & 15, ar = tid >> 4;
  int bc = tid & 63, br = tid >> 6;
  int tx = tid & 15, ty = tid >> 4;
  const float* st = g_state[0];
  int aoff[4];
#pragma unroll
  for (int s = 0; s < 4; ++s) {
    int row = mBase + ar + s * 16;
    if (row > kM0 - 1) row = kM0 - 1;
    int n = row / 31, j = row - n * 31;
    aoff[s] = (n * 4) * 8192 + j * 256;
  }
  float acc[4][4] = {};
  for (int k0 = 0; k0 < 512; k0 += 16) {
#pragma unroll
    for (int s = 0; s < 4; ++s) As[ac][ar + s * 16] = st[aoff[s] + k0 + ac];
#pragma unroll
    for (int s = 0; s < 4; ++s)
      Bs[br + s * 4][bc] = w1[(size_t)(k0 + br + s * 4) * 1024 + nBase + bc];
    __syncthreads();
#pragma unroll
    for (int kk = 0; kk < 16; ++kk) {
      float4 a4 = *(const float4*)&As[kk][ty * 4];
      float4 b4 = *(const float4*)&Bs[kk][tx * 4];
      float av[4] = {a4.x, a4.y, a4.z, a4.w};
      float bv[4] = {b4.x, b4.y, b4.z, b4.w};
#pragma unroll
      for (int ii = 0; ii < 4; ++ii)
#pragma unroll
        for (int jj = 0; jj < 4; ++jj)
          acc[ii][jj] = fmaf(av[ii], bv[jj], acc[ii][jj]);
    }
    __syncthreads();
  }
#pragma unroll
  for (int ii = 0; ii < 4; ++ii) {
    int m = mBase + ty * 4 + ii;
    if (m >= kM0) continue;
#pragma unroll
    for (int jj = 0; jj < 4; ++jj) {
      int n = nBase + tx * 4 + jj;
      g_inter0[(size_t)m * 1024 + n] = geluf(acc[ii][jj] + b1[n]);
    }
  }
}

__global__ __launch_bounds__(256) void k_g2full(const float* __restrict__ w2,
                                                const float* __restrict__ b2) {
  __shared__ float As[16][68];
  __shared__ float Bs[16][64];
  int tid = threadIdx.x;
  int nBase = blockIdx.x * 64, mBase = blockIdx.y * 64;
  int ac = tid & 15, ar = tid >> 4;
  int bc = tid & 63, br = tid >> 6;
  int tx = tid & 15, ty = tid >> 4;
  int arow[4];
#pragma unroll
  for (int s = 0; s < 4; ++s) {
    int row = mBase + ar + s * 16;
    arow[s] = (row > kM0 - 1) ? (kM0 - 1) : row;
  }
  float acc[4][4] = {};
  for (int k0 = 0; k0 < 1024; k0 += 16) {
#pragma unroll
    for (int s = 0; s < 4; ++s)
      As[ac][ar + s * 16] = g_inter0[(size_t)arow[s] * 1024 + k0 + ac];
#pragma unroll
    for (int s = 0; s < 4; ++s)
      Bs[br + s * 4][bc] = w2[(size_t)(k0 + br + s * 4) * 1024 + nBase + bc];
    __syncthreads();
#pragma unroll
    for (int kk = 0; kk < 16; ++kk) {
      float4 a4 = *(const float4*)&As[kk][ty * 4];
      float4 b4 = *(const float4*)&Bs[kk][tx * 4];
      float av[4] = {a4.x, a4.y, a4.z, a4.w};
      float bv[4] = {b4.x, b4.y, b4.z, b4.w};
#pragma unroll
      for (int ii = 0; ii < 4; ++ii)
#pragma unroll
        for (int jj = 0; jj < 4; ++jj)
          acc[ii][jj] = fmaf(av[ii], bv[jj], acc[ii][jj]);
    }
    __syncthreads();
  }
#pragma unroll
  for (int ii = 0; ii < 4; ++ii) {
    int m = mBase + ty * 4 + ii;
    if (m >= kM0) continue;
#pragma unroll
    for (int jj = 0; jj < 4; ++jj) {
      int n = nBase + tx * 4 + jj;
      g_cont0[(size_t)m * 1024 + n] = acc[ii][jj] + b2[n];
    }
  }
}

__global__ __launch_bounds__(256) void k_cellfull(const float* __restrict__ imask,
                                                  const float* __restrict__ ln2g,
                                                  const float* __restrict__ ln2b,
                                                  const float* __restrict__ decW) {
  int m = blockIdx.x;    // n*31 + j
  int d = threadIdx.x;
  int n = m / 31, j = m - n * 31;
  const float* st = g_state[0] + (n * 4) * 8192;
  const float* crow = g_cont0 + (size_t)m * kCH;
  float c0 = crow[d], c1 = crow[kD + d], c2 = crow[2 * kD + d], c3 = crow[3 * kD + d];
  float l = st[j * kD + d];
  float r = st[(j + 1) * kD + d];
  float f1 = 1.0f / (1.0f + expf(-c0));
  float f2 = 1.0f / (1.0f + expf(-c1));
  float ig = 1.0f / (1.0f + expf(-c2));
  float pre = f1 * l + f2 * r + ig * c3;
  __shared__ float red4[4];
  __shared__ float w5[4][5];
  float mean = blockSum256(pre, red4, d) * (1.0f / 256.0f);
  float cen = pre - mean;
  float var = blockSum256(cen * cen, red4, d) * (1.0f / 256.0f);
  float nh = cen / sqrtf(var + 1e-5f) * ln2g[d] + ln2b[d];
  g_nh0[m * kD + d] = nh;
  float mv = imask[n * kS + 1 + j];
  float nhm = nh * mv;
  float pv[5];
#pragma unroll
  for (int t = 0; t < 5; ++t) pv[t] = nhm * decW[t * kD + d];
#pragma unroll
  for (int t = 0; t < 5; ++t)
#pragma unroll
    for (int o = 32; o > 0; o >>= 1) pv[t] += __shfl_down(pv[t], o, 64);
  __syncthreads();
  if ((d & 63) == 0) {
#pragma unroll
    for (int t = 0; t < 5; ++t) w5[d >> 6][t] = pv[t];
  }
  __syncthreads();
  if (d < 5) g_s50[m * 5 + d] = w5[0][d] + w5[1][d] + w5[2][d] + w5[3][d];
}

// ---------------- incremental GEMMs (128 slot rows) ----------------
__global__ __launch_bounds__(256) void k_g1inc(const float* __restrict__ w1,
                                               const float* __restrict__ b1, int buf) {
  __shared__ float As[16][17];
  __shared__ float Bs[16][64];
  int tid = threadIdx.x;
  int nBase = blockIdx.x * 64, mBase = blockIdx.y * 16;
  int am = tid >> 4, akk = tid & 15;
  int bc = tid & 63, br = tid >> 6;
  int tx = tid & 15, ty = tid >> 4;
  int s = mBase + am;
  int b = s >> 1;
  int j = g_slots[s]; if (j < 0) j = 0;
  const float* Arow = g_state[buf] + b * 8192 + j * 256;  // contiguous 512 (l,r)
  float acc[4] = {0.f, 0.f, 0.f, 0.f};
  for (int k0 = 0; k0 < 512; k0 += 16) {
    As[akk][am] = Arow[k0 + akk];
#pragma unroll
    for (int s4 = 0; s4 < 4; ++s4)
      Bs[br + s4 * 4][bc] = w1[(size_t)(k0 + br + s4 * 4) * 1024 + nBase + bc];
    __syncthreads();
#pragma unroll
    for (int kk = 0; kk < 16; ++kk) {
      float a = As[kk][ty];
      float4 b4 = *(const float4*)&Bs[kk][tx * 4];
      acc[0] = fmaf(a, b4.x, acc[0]);
      acc[1] = fmaf(a, b4.y, acc[1]);
      acc[2] = fmaf(a, b4.z, acc[2]);
      acc[3] = fmaf(a, b4.w, acc[3]);
    }
    __syncthreads();
  }
  int om = mBase + ty;
  float4 o4;
  o4.x = geluf(acc[0] + b1[nBase + tx * 4 + 0]);
  o4.y = geluf(acc[1] + b1[nBase + tx * 4 + 1]);
  o4.z = geluf(acc[2] + b1[nBase + tx * 4 + 2]);
  o4.w = geluf(acc[3] + b1[nBase + tx * 4 + 3]);
  *(float4*)&g_interI[om * 1024 + nBase + tx * 4] = o4;
}

__global__ __launch_bounds__(256) void k_g2inc(const float* __restrict__ w2) {
  __shared__ float As[16][17];
  __shared__ float Bs[16][64];
  int tid = threadIdx.x;
  int nBase = blockIdx.x * 64, mBase = blockIdx.y * 16;
  int kBase = blockIdx.z * 256;
  int am = tid >> 4, akk = tid & 15;
  int bc = tid & 63, br = tid >> 6;
  int tx = tid & 15, ty = tid >> 4;
  const float* Arow = g_interI + (mBase + am) * 1024;
  float acc[4] = {0.f, 0.f, 0.f, 0.f};
  for (int k0 = kBase; k0 < kBase + 256; k0 += 16) {
    As[akk][am] = Arow[k0 + akk];
#pragma unroll
    for (int s4 = 0; s4 < 4; ++s4)
      Bs[br + s4 * 4][bc] = w2[(size_t)(k0 + br + s4 * 4) * 1024 + nBase + bc];
    __syncthreads();
#pragma unroll
    for (int kk = 0; kk < 16; ++kk) {
      float a = As[kk][ty];
      float4 b4 = *(const float4*)&Bs[kk][tx * 4];
      acc[0] = fmaf(a, b4.x, acc[0]);
      acc[1] = fmaf(a, b4.y, acc[1]);
      acc[2] = fmaf(a, b4.z, acc[2]);
      acc[3] = fmaf(a, b4.w, acc[3]);
    }
    __syncthreads();
  }
  int om = mBase + ty;
  float4 o4 = {acc[0], acc[1], acc[2], acc[3]};
  *(float4*)&g_contP[blockIdx.z][om * 1024 + nBase + tx * 4] = o4;
}

__global__ __launch_bounds__(256) void k_cellinc(const float* __restrict__ imask,
                                                 const float* __restrict__ ln2g,
                                                 const float* __restrict__ ln2b,
                                                 const float* __restrict__ decW,
                                                 const float* __restrict__ b2,
                                                 int step, int buf) {
  int s = blockIdx.x;
  int d = threadIdx.x;
  int b = s >> 1;
  int j = g_slots[s];
  if (j < 0) return;  // block-uniform
  float c[4];
#pragma unroll
  for (int q = 0; q < 4; ++q) {
    int col = q * 256 + d;
    float v = ((g_contP[0][s * 1024 + col] + g_contP[1][s * 1024 + col]) +
               g_contP[2][s * 1024 + col]) + g_contP[3][s * 1024 + col];
    c[q] = v + b2[col];
  }
  const float* st = g_state[buf] + b * 8192;
  float l = st[j * kD + d];
  float r = st[(j + 1) * kD + d];
  float f1 = 1.0f / (1.0f + expf(-c[0]));
  float f2 = 1.0f / (1.0f + expf(-c[1]));
  float ig = 1.0f / (1.0f + expf(-c[2]));
  float pre = f1 * l + f2 * r + ig * c[3];
  __shared__ float red4[4];
  __shared__ float w5[4][5];
  float mean = blockSum256(pre, red4, d) * (1.0f / 256.0f);
  float cen = pre - mean;
  float var = blockSum256(cen * cen, red4, d) * (1.0f / 256.0f);
  float nh = cen / sqrtf(var + 1e-5f) * ln2g[d] + ln2b[d];
  g_nh[buf][((size_t)b * kP0 + j) * kD + d] = nh;
  float mv = imask[(b >> 2) * kS + step + 1 + j];
  float nhm = nh * mv;
  float pv[5];
#pragma unroll
  for (int t = 0; t < 5; ++t) pv[t] = nhm * decW[t * kD + d];
#pragma unroll
  for (int t = 0; t < 5; ++t)
#pragma unroll
    for (int o = 32; o > 0; o >>= 1) pv[t] += __shfl_down(pv[t], o, 64);
  __syncthreads();
  if ((d & 63) == 0) {
#pragma unroll
    for (int t = 0; t < 5; ++t) w5[d >> 6][t] = pv[t];
  }
  __syncthreads();
  if (d < 5) g_s5[buf][((size_t)b * kP0 + j) * 5 + d] = w5[0][d] + w5[1][d] + w5[2][d] + w5[3][d];
}

// ---------------- merge with embedded Gumbel decision (steps 0..29) ----------------
__global__ __launch_bounds__(256) void k_merge(const float* __restrict__ imask,
                                               const float* __restrict__ decW,
                                               const float* __restrict__ decb,
                                               int step) {
  int b = blockIdx.x, jrow = blockIdx.y;
  int tid = threadIdx.x;
  int Sc = 31 - step;                 // pair count = new state length
  int nIdx = (step == 0);
  int n32 = (b >> 2) * kS;
  const float* stOld = g_state[step & 1] + b * 8192;
  float* stNew = g_state[(step + 1) & 1] + b * 8192;
  const float* nhSrc = nIdx ? (g_nh0 + (size_t)(b >> 2) * kP0 * kD)
                            : (g_nh[step & 1] + (size_t)b * kP0 * kD);
  const float* s5Src = nIdx ? (g_s50 + (b >> 2) * kP0 * 5)
                            : (g_s5[step & 1] + b * kP0 * 5);
  float* nhDst = g_nh[(step + 1) & 1] + (size_t)b * kP0 * kD;
  float* s5Dst = g_s5[(step + 1) & 1] + b * kP0 * 5;
  float done = imask[n32 + step + 1];

  __shared__ int sh_k;
  __shared__ float sh_sv;
  __shared__ float w5[4][5];
  if (tid < 64) {
    int j = tid;
    bool act = j < Sc;
    float mv = 0.f, lg = 0.f;
    if (act) {
      mv = imask[n32 + step + 1 + j];
      float t = decb[0];
      if (j >= 2) t += s5Src[(j - 2) * 5 + 0];
      if (j >= 1) t += s5Src[(j - 1) * 5 + 1];
      t += s5Src[j * 5 + 2];
      if (j + 1 < Sc) t += s5Src[(j + 1) * 5 + 3];
      if (j + 2 < Sc) t += s5Src[(j + 2) * 5 + 4];
      lg = t / 35.77708763999664f;
    }
    uint32_t fk0, fk1, o0, o1;
    tf2x32(0u, 1234u, 0u, (uint32_t)step, fk0, fk1);
    uint32_t idx = (uint32_t)(b * Sc + j);
    tf2x32(fk0, fk1, 0u, idx, o0, o1);
    uint32_t bits = o0 ^ o1;
    float u = __uint_as_float((bits >> 9) | 0x3f800000u) - 1.0f;
    float gum = -logf(-logf(u + 1e-20f) + 1e-20f);
    float z = lg + gum;
    float zm = waveMax64(act ? z : -3.0e38f);
    float e = act ? expf(z - zm) : 0.f;
    float p = e / waveSum64(e);
    float y = act ? (p * mv + 1e-20f) : 0.f;
    float ys = y / waveSum64(y);
    float av = act ? ys : -1.f;
    int ai = j;
#pragma unroll
    for (int o = 32; o > 0; o >>= 1) {
      float ov = __shfl_xor(av, o, 64);
      int oi = __shfl_xor(ai, o, 64);
      if (ov > av || (ov == av && oi < ai)) { av = ov; ai = oi; }
    }
    float lm = waveMax64(act ? lg : -3.0e38f);
    float e2 = act ? expf(lg - lm) : 0.f;
    float p2 = e2 / waveSum64(e2);
    float y2 = act ? (p2 * mv + 1e-20f) : 0.f;
    float ps = y2 / waveSum64(y2);
    float ysk = __shfl(ys, ai, 64);
    float psk = __shfl(ps, ai, 64);
    float sv = (1.0f - ysk) + ysk;
    if (j == 0) {
      sh_k = ai;
      sh_sv = sv;
      if (jrow == 0) {
        g_accu[b] += done * logf(sv * psk + 1e-20f);
        int s0 = -1, s1 = -1;
        if (done != 0.0f) {
          if (ai >= 1) s0 = ai - 1;
          if (ai <= Sc - 2) s1 = ai;
        }
        g_slots[2 * b] = s0;
        g_slots[2 * b + 1] = s1;
      }
    }
  }
  __syncthreads();
  int k = sh_k;
  float sv = sh_sv;
  int d = tid;
  float oldl = stOld[jrow * kD + d];
  if (done != 0.0f) {
    float merged;
    if (jrow < k) {
      merged = oldl;
    } else if (jrow == k) {
      float nhk = nhSrc[k * kD + d];
      merged = sv * nhk + (1.0f - sv) * oldl;
    } else {
      float oldr = stOld[(jrow + 1) * kD + d];
      merged = (1.0f - sv) * oldl + sv * oldr;
    }
    stNew[jrow * kD + d] = done * merged + (1.0f - done) * oldl;
  } else {
    stNew[jrow * kD + d] = oldl;
  }
  int pairsNew = Sc - 1;
  if (jrow < pairsNew) {
    int src = (done != 0.0f && jrow > k) ? jrow + 1 : jrow;
    float nv = nhSrc[src * kD + d];
    nhDst[jrow * kD + d] = nv;
    float mv2 = imask[n32 + step + 2 + jrow];
    float nhm = nv * mv2;
    float pv[5];
#pragma unroll
    for (int t = 0; t < 5; ++t) pv[t] = nhm * decW[t * kD + d];
#pragma unroll
    for (int t = 0; t < 5; ++t)
#pragma unroll
      for (int o = 32; o > 0; o >>= 1) pv[t] += __shfl_down(pv[t], o, 64);
    __syncthreads();
    if ((d & 63) == 0) {
#pragma unroll
      for (int t = 0; t < 5; ++t) w5[d >> 6][t] = pv[t];
    }
    __syncthreads();
    if (d < 5) s5Dst[jrow * 5 + d] = w5[0][d] + w5[1][d] + w5[2][d] + w5[3][d];
  }
}

// ---------------- last step (i=30): no select ----------------
__global__ __launch_bounds__(256) void k_mergelast(const float* __restrict__ imask,
                                                   int step) {
  int b = blockIdx.x;
  int d = threadIdx.x;
  int n32 = (b >> 2) * kS;
  float done = imask[n32 + step + 1];
  const float* stOld = g_state[step & 1] + b * 8192;
  float* stNew = g_state[(step + 1) & 1] + b * 8192;
  float nh = g_nh[step & 1][((size_t)b * kP0 + 0) * kD + d];
  stNew[d] = done * nh + (1.0f - done) * stOld[d];
}

__global__ __launch_bounds__(256) void k_final(float* __restrict__ out) {
  int n = blockIdx.x, d = threadIdx.x;
  float a0 = g_accu[n * 4 + 0], a1 = g_accu[n * 4 + 1];
  float a2 = g_accu[n * 4 + 2], a3 = g_accu[n * 4 + 3];
  float mx = fmaxf(fmaxf(a0, a1), fmaxf(a2, a3));
  float e0 = expf(a0 - mx), e1 = expf(a1 - mx), e2 = expf(a2 - mx), e3 = expf(a3 - mx);
  float ssum = e0 + e1 + e2 + e3;
  const float* st = g_state[1];
  float h0 = st[(n * 4 + 0) * 8192 + d];
  float h1 = st[(n * 4 + 1) * 8192 + d];
  float h2 = st[(n * 4 + 2) * 8192 + d];
  float h3 = st[(n * 4 + 3) * 8192 + d];
  out[n * kD + d] = (e0 / ssum) * h0 + (e1 / ssum) * h1 + (e2 / ssum) * h2 + (e3 / ssum) * h3;
}

extern "C" void kernel_launch(void* const* d_in, const int* in_sizes, int n_in,
                              void* d_out, int out_size, void* d_ws, size_t ws_size,
                              hipStream_t stream) {
  (void)in_sizes; (void)n_in; (void)d_ws; (void)ws_size; (void)out_size;
  const float* x = (const float*)d_in[0];
  const float* imask = (const float*)d_in[1];
  const float* wW = (const float*)d_in[2];
  const float* wb = (const float*)d_in[3];
  const float* lng = (const float*)d_in[4];
  const float* lnb = (const float*)d_in[5];
  const float* w1 = (const float*)d_in[6];
  const float* b1 = (const float*)d_in[7];
  const float* w2 = (const float*)d_in[8];
  const float* b2 = (const float*)d_in[9];
  const float* ln2g = (const float*)d_in[10];
  const float* ln2b = (const float*)d_in[11];
  const float* decW = (const float*)d_in[12];
  const float* decb = (const float*)d_in[13];
  float* out = (float*)d_out;

  k_embed<<<dim3(512), dim3(256), 0, stream>>>(x, wW, wb, lng, lnb);
  k_g1full<<<dim3(16, 8), dim3(256), 0, stream>>>(w1, b1);
  k_g2full<<<dim3(16, 8), dim3(256), 0, stream>>>(w2, b2);
  k_cellfull<<<dim3(kM0), dim3(256), 0, stream>>>(imask, ln2g, ln2b, decW);
  k_merge<<<dim3(kNB, 31), dim3(256), 0, stream>>>(imask, decW, decb, 0);
  for (int i = 1; i <= 30; ++i) {
    k_g1inc<<<dim3(16, 8), dim3(256), 0, stream>>>(w1, b1, i & 1);
    k_g2inc<<<dim3(16, 8, 4), dim3(256), 0, stream>>>(w2);
    k_cellinc<<<dim3(128), dim3(256), 0, stream>>>(imask, ln2g, ln2b, decW, b2, i, i & 1);
    if (i < 30)
      k_merge<<<dim3(kNB, 31 - i), dim3(256), 0, stream>>>(imask, decW, decb, i);
    else
      k_mergelast<<<dim3(kNB), dim3(256), 0, stream>>>(imask, i);
  }
  k_final<<<dim3(16), dim3(256), 0, stream>>>(out);
}